// Round 7
// baseline (237.475 us; speedup 1.0000x reference)
//
#include <hip/hip_runtime.h>
#include <math.h>

#define EPS_N 1e-12f
#define MARGIN 0.3f
#define INF_BITS 0x7f800000u
#define NCLS 128     // label space (randint(0,128))
#define D 512
#define PADR 256     // padded rows after fh (kept for safety margins)

typedef __attribute__((ext_vector_type(8))) short short8;   // 8 bf16 = 4 VGPRs
typedef __attribute__((ext_vector_type(4))) float float4v;  // MFMA 16x16 accum

__device__ __forceinline__ unsigned short f2bf(float f) {   // RNE bf16
    unsigned u = __float_as_uint(f);
    u += 0x7fff + ((u >> 16) & 1);
    return (unsigned short)(u >> 16);
}
__device__ __forceinline__ void gl16(const void* g, void* l) {
    // 16B async global->LDS; global addr per-lane, LDS dest = uniform base + lane*16
    __builtin_amdgcn_global_load_lds((const __attribute__((address_space(1))) void*)g,
                                     (__attribute__((address_space(3))) void*)l, 16, 0, 0);
}

// ---------------------------------------------------------------------------
// K0: one-block bucketing, coalesced-metadata (unchanged).
// ---------------------------------------------------------------------------
__global__ __launch_bounds__(1024) void k_bucket(const int* __restrict__ lab, int Bn,
        int* __restrict__ pos, int* __restrict__ labp,
        int* __restrict__ cstart_g, int* __restrict__ ccnt_g,
        float* __restrict__ meanpos, float* __restrict__ pcinv,
        int* __restrict__ poscnt, unsigned* __restrict__ minbits) {
    __shared__ int cnt[NCLS], cs[NCLS + 1], off[NCLS], sa[NCLS], sb[NCLS];
    int tid = threadIdx.x;
    if (tid < NCLS) cnt[tid] = 0;
    __syncthreads();
    for (int i = tid; i < Bn; i += 1024) atomicAdd(&cnt[lab[i] & (NCLS - 1)], 1);
    __syncthreads();
    if (tid < NCLS) sa[tid] = cnt[tid];
    __syncthreads();
    int* src = sa; int* dst = sb;
    for (int ofs = 1; ofs < NCLS; ofs <<= 1) {          // Hillis-Steele inclusive
        if (tid < NCLS) dst[tid] = src[tid] + ((tid >= ofs) ? src[tid - ofs] : 0);
        __syncthreads();
        int* t = src; src = dst; dst = t;
    }
    if (tid < NCLS) {
        int ex = src[tid] - cnt[tid];                   // exclusive
        cs[tid] = ex;
        off[tid] = ex;
        cstart_g[tid] = ex;
        ccnt_g[tid] = cnt[tid];
    }
    if (tid == 0) cs[NCLS] = Bn;
    __syncthreads();
    // coalesced per-slot metadata: class(p) = largest l with cs[l] <= p
    for (int p = tid; p < Bn; p += 1024) {
        int lo = 0, hi = NCLS - 1;
        #pragma unroll
        for (int s = 0; s < 7; ++s) {
            int mid = (lo + hi + 1) >> 1;
            if (cs[mid] <= p) lo = mid; else hi = mid - 1;
        }
        int l = lo, m = cnt[l];
        labp[p] = l;
        poscnt[p] = m;
        pcinv[p] = 1.0f / (float)m;
        meanpos[p] = 0.f;
        minbits[p] = INF_BITS;
    }
    // pos scatter (reads coalesced; only pos[] store is scattered-by-class)
    for (int i = tid; i < Bn; i += 1024) {
        int l = lab[i] & (NCLS - 1);
        pos[i] = atomicAdd(&off[l], 1);
    }
}

// ---------------------------------------------------------------------------
// K1: normalize; one wave per row, no __syncthreads (unchanged).
// ---------------------------------------------------------------------------
__global__ __launch_bounds__(256) void k_normalize(const float* __restrict__ x,
        const int* __restrict__ pos, unsigned short* __restrict__ fh,
        float* __restrict__ sqp) {
    int w = threadIdx.x >> 6, L = threadIdx.x & 63;
    int row = blockIdx.x * 4 + w;
    const float* xr = x + (size_t)row * D + L * 8;
    float4 a = *(const float4*)xr;
    float4 b = *(const float4*)(xr + 4);
    float ss = a.x * a.x;
    ss = fmaf(a.y, a.y, ss); ss = fmaf(a.z, a.z, ss); ss = fmaf(a.w, a.w, ss);
    ss = fmaf(b.x, b.x, ss); ss = fmaf(b.y, b.y, ss);
    ss = fmaf(b.z, b.z, ss); ss = fmaf(b.w, b.w, ss);
    #pragma unroll
    for (int off = 32; off; off >>= 1) ss += __shfl_xor(ss, off, 64);
    float inv = 1.0f / fmaxf(sqrtf(ss), EPS_N);
    int prow = pos[row];
    if (L == 0) sqp[prow] = ss * inv * inv;
    ushort4 h0, h1;
    h0.x = f2bf(a.x * inv); h0.y = f2bf(a.y * inv);
    h0.z = f2bf(a.z * inv); h0.w = f2bf(a.w * inv);
    h1.x = f2bf(b.x * inv); h1.y = f2bf(b.y * inv);
    h1.z = f2bf(b.z * inv); h1.w = f2bf(b.w * inv);
    unsigned short* dst = fh + (size_t)prow * D + L * 8;
    *(ushort4*)dst = h0;
    *(ushort4*)(dst + 4) = h1;
}

// ---------------------------------------------------------------------------
// K2: per-class positive stats (unchanged from R17; passed).
// ---------------------------------------------------------------------------
__global__ __launch_bounds__(256) void k_posclass(
    const unsigned short* __restrict__ fh, const float* __restrict__ sqp,
    const int* __restrict__ cstart_g, const int* __restrict__ ccnt_g,
    float* __restrict__ meanpos)
{
    const int c = blockIdx.x;
    const int s = cstart_g[c], n = ccnt_g[c];
    if (n <= 1) return;                         // no positives; meanpos stays 0

    __shared__ unsigned short SA[128 * 128];    // row chunk   [r][K128] 32 KB
    __shared__ unsigned short SB[128 * 128];    // col chunk   [r][K128] 32 KB
    __shared__ float sqr_sh[128], sqs[128], rs[128];

    const int tid = threadIdx.x, w = tid >> 6, L = tid & 63;
    const int lm = L & 15, ls = L >> 4;

    for (int rb = 0; rb < n; rb += 128) {
        const int nr = min(128, n - rb);
        __syncthreads();
        if (tid < 128) {
            rs[tid] = 0.f;
            sqr_sh[tid] = (tid < nr) ? sqp[s + rb + tid] : 0.f;
        }
        for (int cb = 0; cb < n; cb += 128) {
            const int m = min(128, n - cb);
            const bool same = (rb == cb);
            __syncthreads();                    // prior epilogue done; sqs free
            if (tid < 128) sqs[tid] = (tid < m) ? sqp[s + cb + tid] : 0.f;

            float4v acc[8][2];
            #pragma unroll
            for (int rt = 0; rt < 8; ++rt)
                #pragma unroll
                for (int ct = 0; ct < 2; ++ct) acc[rt][ct] = (float4v){0.f, 0.f, 0.f, 0.f};

            for (int k0 = 0; k0 < D; k0 += 128) {
                __syncthreads();                // prev MFMA reads done; bufs free
                #pragma unroll
                for (int q = 0; q < 8; ++q) {
                    int slot = tid + 256 * q;   // (row r = slot>>4, seg e = slot&15)
                    int r = slot >> 4;
                    int u = (slot & 15) ^ (r & 15);   // pre-swizzled global seg
                    if (r < nr)
                        gl16(fh + (size_t)(s + rb + r) * D + k0 + u * 8,
                             &SA[(w * 64 + 256 * q) * 8]);
                }
                if (!same) {
                    #pragma unroll
                    for (int q = 0; q < 8; ++q) {
                        int slot = tid + 256 * q;
                        int r = slot >> 4;
                        int u = (slot & 15) ^ (r & 15);
                        if (r < m)
                            gl16(fh + (size_t)(s + cb + r) * D + k0 + u * 8,
                                 &SB[(w * 64 + 256 * q) * 8]);
                    }
                }
                __syncthreads();                // drains vmcnt: chunk landed
                const unsigned short* Bb = same ? SA : SB;
                #pragma unroll
                for (int h = 0; h < 4; ++h) {   // K=128 in 4 MFMA sub-steps
                    short8 bf[2];
                    #pragma unroll
                    for (int ct = 0; ct < 2; ++ct) {
                        int cr = w * 32 + ct * 16 + lm;
                        bf[ct] = *(const short8*)&Bb[cr * 128 + (((h * 4 + ls) ^ (cr & 15))) * 8];
                    }
                    #pragma unroll
                    for (int rt = 0; rt < 8; ++rt) {
                        int ar = rt * 16 + lm;
                        short8 af = *(const short8*)&SA[ar * 128 + (((h * 4 + ls) ^ (ar & 15))) * 8];
                        #pragma unroll
                        for (int ct = 0; ct < 2; ++ct)
                            acc[rt][ct] = __builtin_amdgcn_mfma_f32_16x16x32_bf16(af, bf[ct], acc[rt][ct], 0, 0, 0);
                    }
                }
            }
            // epilogue: masked dist row-sums. C/D: row = rt*16+ls*4+v, col = w*32+ct*16+lm
            #pragma unroll
            for (int rt = 0; rt < 8; ++rt) {
                #pragma unroll
                for (int v = 0; v < 4; ++v) {
                    int ri = rt * 16 + ls * 4 + v;
                    float sr = sqr_sh[ri];
                    float sum = 0.f;
                    #pragma unroll
                    for (int ct = 0; ct < 2; ++ct) {
                        int ci = w * 32 + ct * 16 + lm;
                        float d2 = sr + sqs[ci] - 2.0f * acc[rt][ct][v];
                        bool ok = (ri < nr) && (ci < m) && (rb + ri != cb + ci) && (d2 > 0.f);
                        sum += ok ? sqrtf(d2) : 0.f;
                    }
                    #pragma unroll
                    for (int off = 8; off; off >>= 1) sum += __shfl_xor(sum, off, 64);
                    if (lm == 0 && sum != 0.f) atomicAdd(&rs[ri], sum);
                }
            }
        }
        __syncthreads();
        if (tid < nr) meanpos[s + rb + tid] = rs[tid];   // single writer: plain store
    }
}

// ---------------------------------------------------------------------------
// K3 (R18): GLOBAL-DIRECT register MFMA. fh (8.4 MB) is L2/L3-hot; the
// 16x16x32 A/B fragments are contiguous 16B/lane, so load them straight from
// global to VGPRs: no LDS staging, no LDS reads, ZERO K-loop barriers.
// R16 showed the LDS path is LDS-BW-bound (1.6 GB LDS traffic -> ~64 us at
// its ceiling); direct path moves 1.06 GB through L2 (34.5-37 TB/s) with
// latency hidden by 16 waves/CU TLP (4 blocks/CU). All k-offsets are
// immediate-foldable (kt*64B <= 960). XCD-bijective swizzle (2080 = 8*260)
// keeps each XCD's B-panel L2-hot across its 260-tile chunk.
// 128x128 triangular tiles, dual-side d2 epilogue (R8-verified).
// ---------------------------------------------------------------------------
__global__ __launch_bounds__(256, 4) void k_minsh_mfma(
    const unsigned short* __restrict__ fh, const float* __restrict__ sqp,
    const int* __restrict__ labp, const float* __restrict__ meanpos,
    const float* __restrict__ pcinv, unsigned* __restrict__ minbits)
{
    // XCD-bijective swizzle + triangular decode
    int t = (blockIdx.x & 7) * 260 + (blockIdx.x >> 3);
    int rq = (int)((sqrtf(8.0f * (float)t + 1.0f) - 1.0f) * 0.5f);
    while ((rq + 1) * (rq + 2) / 2 <= t) ++rq;
    while (rq * (rq + 1) / 2 > t) --rq;
    int cq = t - rq * (rq + 1) / 2;
    const int i0 = cq * 128, j0 = rq * 128;
    const bool diag = (i0 == j0);

    __shared__ float s_mp2r[128], s_mp2c[128], s_sqr[128], s_sqc[128];
    __shared__ int s_labr[128], s_labc[128];

    const int tid = threadIdx.x;
    const int w = tid >> 6, L = tid & 63;
    const int lm = L & 15, ls = L >> 4;
    const int rw = (w >> 1) * 64, cw = (w & 1) * 64;

    if (tid < 128) {
        float mp = meanpos[i0 + tid] * pcinv[i0 + tid];
        s_mp2r[tid] = mp * mp;
        s_sqr[tid]  = sqp[i0 + tid];
        s_labr[tid] = labp[i0 + tid];
    } else {
        int q = tid - 128;
        float mp = meanpos[j0 + q] * pcinv[j0 + q];
        s_mp2c[q] = mp * mp;
        s_sqc[q]  = sqp[j0 + q];
        s_labc[q] = labp[j0 + q];
    }

    // per-lane fragment bases: A frag(mi,kt) = pa + mi*16*D + kt*32 (ushorts)
    const unsigned short* pa = fh + (size_t)(i0 + rw + lm) * D + ls * 8;
    const unsigned short* pb = fh + (size_t)(j0 + cw + lm) * D + ls * 8;

    float4v acc[4][4];
    #pragma unroll
    for (int a = 0; a < 4; ++a)
        #pragma unroll
        for (int bq = 0; bq < 4; ++bq) acc[a][bq] = (float4v){0.f, 0.f, 0.f, 0.f};

    #pragma unroll 2
    for (int kt = 0; kt < 16; ++kt) {           // K=32 per step
        short8 ah[4], bh[4];
        #pragma unroll
        for (int mi = 0; mi < 4; ++mi)
            ah[mi] = *(const short8*)(pa + mi * 16 * D + kt * 32);
        #pragma unroll
        for (int ni = 0; ni < 4; ++ni)
            bh[ni] = *(const short8*)(pb + ni * 16 * D + kt * 32);
        #pragma unroll
        for (int ni = 0; ni < 4; ++ni)
            #pragma unroll
            for (int mi = 0; mi < 4; ++mi)
                acc[mi][ni] = __builtin_amdgcn_mfma_f32_16x16x32_bf16(ah[mi], bh[ni], acc[mi][ni], 0, 0, 0);
    }
    __syncthreads();                            // metadata visible (only barrier)

    // d2-space epilogue. C/D: row = rw+mi*16+ls*4+v, col = cw+ni*16+lm
    const float INFF = __uint_as_float(INF_BITS);
    float sc[4], mp2c[4];
    int lc[4];
    #pragma unroll
    for (int ni = 0; ni < 4; ++ni) {
        int cl = cw + ni * 16 + lm;
        sc[ni]   = s_sqc[cl];
        mp2c[ni] = s_mp2c[cl];
        lc[ni]   = s_labc[cl];
    }
    float vminc[4];
    #pragma unroll
    for (int ni = 0; ni < 4; ++ni) vminc[ni] = INFF;

    #pragma unroll
    for (int mi = 0; mi < 4; ++mi) {
        #pragma unroll
        for (int v = 0; v < 4; ++v) {
            int rl = rw + mi * 16 + ls * 4 + v;
            float mp2r = s_mp2r[rl];
            float sr   = s_sqr[rl];
            int   li   = s_labr[rl];
            float vminr = INFF;
            #pragma unroll
            for (int ni = 0; ni < 4; ++ni) {
                float d2 = fmaf(-2.0f, acc[mi][ni][v], sr + sc[ni]);
                bool neq = (li != lc[ni]);
                vminr     = fminf(vminr,     (neq && d2 > mp2r)     ? d2 : INFF);
                vminc[ni] = fminf(vminc[ni], (neq && d2 > mp2c[ni]) ? d2 : INFF);
            }
            #pragma unroll
            for (int off = 8; off; off >>= 1)
                vminr = fminf(vminr, __shfl_xor(vminr, off, 64));
            if (lm == 0 && __float_as_uint(vminr) != INF_BITS)
                atomicMin(&minbits[i0 + rl], __float_as_uint(vminr));
        }
    }
    if (!diag) {
        #pragma unroll
        for (int ni = 0; ni < 4; ++ni) {
            float vc = vminc[ni];
            vc = fminf(vc, __shfl_xor(vc, 16, 64));
            vc = fminf(vc, __shfl_xor(vc, 32, 64));
            if (ls == 0 && __float_as_uint(vc) != INF_BITS)
                atomicMin(&minbits[j0 + cw + ni * 16 + lm], __float_as_uint(vc));
        }
    }
}

// ---------------------------------------------------------------------------
// K4: final reduction (unchanged).
// ---------------------------------------------------------------------------
__global__ __launch_bounds__(1024) void k_finish(const float* __restrict__ meanpos,
        const float* __restrict__ pcinv, const int* __restrict__ poscnt,
        const unsigned* __restrict__ minbits, float* __restrict__ out, int Bn) {
    float lsum = 0.f; int lcnt = 0;
    for (int i = threadIdx.x; i < Bn; i += 1024) {
        int pc = poscnt[i];
        bool valid = (pc > 1) && (pc < Bn);
        unsigned mb = minbits[i];
        if (valid && mb != INF_BITS) {
            float v = fmaf(meanpos[i], pcinv[i], MARGIN - sqrtf(__uint_as_float(mb)));
            lsum += (v > 0.f) ? v : 0.f;
            lcnt += 1;
        }
    }
    __shared__ float ssum[16]; __shared__ int scnt[16];
    int lane = threadIdx.x & 63, wid = threadIdx.x >> 6;
    #pragma unroll
    for (int off = 32; off; off >>= 1) {
        lsum += __shfl_down(lsum, off, 64);
        lcnt += __shfl_down(lcnt, off, 64);
    }
    if (lane == 0) { ssum[wid] = lsum; scnt[wid] = lcnt; }
    __syncthreads();
    if (threadIdx.x == 0) {
        float s = 0.f; int c = 0;
        #pragma unroll
        for (int q = 0; q < 16; ++q) { s += ssum[q]; c += scnt[q]; }
        out[0] = (c > 0) ? s / (float)c : 0.f;
    }
}

// ---------------------------------------------------------------------------
extern "C" void kernel_launch(void* const* d_in, const int* in_sizes, int n_in,
                              void* d_out, int out_size, void* d_ws, size_t ws_size,
                              hipStream_t stream) {
    const float* x = (const float*)d_in[0];
    const int* lab = (const int*)d_in[1];
    int Bn = in_sizes[1];                 // 8192; D fixed at 512

    size_t nd = (size_t)(Bn + PADR) * D;
    unsigned short* fh = (unsigned short*)d_ws;
    float* sqp        = (float*)(fh + nd);
    float* meanpos    = sqp + Bn;         // raw dist-sums
    float* pcinv      = meanpos + Bn;
    int* poscnt       = (int*)(pcinv + Bn);
    unsigned* minbits = (unsigned*)(poscnt + Bn);
    int* pos          = (int*)(minbits + Bn);
    int* labp         = pos + Bn;
    int* cstart_g     = labp + Bn;
    int* ccnt_g       = cstart_g + NCLS;

    k_bucket<<<1, 1024, 0, stream>>>(lab, Bn, pos, labp, cstart_g, ccnt_g,
                                     meanpos, pcinv, poscnt, minbits);
    k_normalize<<<Bn / 4, 256, 0, stream>>>(x, pos, fh, sqp);
    k_posclass<<<NCLS, 256, 0, stream>>>(fh, sqp, cstart_g, ccnt_g, meanpos);
    int nb = Bn / 128;
    int T = nb * (nb + 1) / 2;            // 2080 = 8*260 (XCD-bijective)
    k_minsh_mfma<<<T, 256, 0, stream>>>(fh, sqp, labp, meanpos, pcinv, minbits);
    k_finish<<<1, 1024, 0, stream>>>(meanpos, pcinv, poscnt, minbits,
                                     (float*)d_out, Bn);
}